// Round 6
// baseline (304.234 us; speedup 1.0000x reference)
//
#include <hip/hip_runtime.h>
#include <math.h>

#define EMBED 1024
#define NHEAD 16
#define HDIM  64
#define CLEN  16384

// ---- workspace layout (float offsets) ----
#define WS_QKV   0          // q[1024] | k_i[1024] | v_i[1024]
#define WS_QP    3072       // qkv split-K partials [3*64*1024]
#define WS_PM    199680     // block-partial m   [1024*16]
#define WS_PL    216064     // block-partial l   [1024*16]
#define WS_PACC  232448     // block-partial acc [1024*1024]
#define WS_GM    1281024    // group m   [32*16]
#define WS_GL    1281536    // group l   [32*16]
#define WS_GACC  1282048    // group acc [32*1024]
#define WS_OPART 1314816    // out-proj partials [64*1024]
// total = 1380352 floats ~= 5.52 MB

// ---------------------------------------------------------------------------
// A: q/k/v projection split-K partials. 192 blocks = 3 matrices x 64 K-chunks
// ---------------------------------------------------------------------------
__global__ __launch_bounds__(256) void qkv_proj(
    const float* __restrict__ x,
    const float* __restrict__ Wq,
    const float* __restrict__ Wk,
    const float* __restrict__ Wv,
    float* __restrict__ ws) {
  int m = blockIdx.x >> 6;             // 0:q 1:k 2:v
  int c = blockIdx.x & 63;             // K-chunk
  const float* W = (m == 0) ? Wq : (m == 1) ? Wk : Wv;
  int j = threadIdx.x << 2;
  int i0 = c * 16;
  float4 acc = make_float4(0.f, 0.f, 0.f, 0.f);
  for (int i = i0; i < i0 + 16; ++i) {
    float xv = x[i];
    float4 w = *(const float4*)(W + (size_t)i * EMBED + j);
    acc.x += xv * w.x; acc.y += xv * w.y;
    acc.z += xv * w.z; acc.w += xv * w.w;
  }
  *(float4*)(ws + WS_QP + (size_t)(m * 64 + c) * EMBED + j) = acc;
}

// A2: reduce 64 partials + bias -> q/k/v. 12 blocks x 256.
__global__ __launch_bounds__(256) void qkv_reduce(
    const float* __restrict__ bq, const float* __restrict__ bk,
    const float* __restrict__ bv, float* __restrict__ ws) {
  int m = blockIdx.x >> 2;
  int j = ((blockIdx.x & 3) << 8) + threadIdx.x;
  const float* b = (m == 0) ? bq : (m == 1) ? bk : bv;
  float s = b[j];
  const float* p = ws + WS_QP + (size_t)m * 64 * EMBED + j;
  for (int c = 0; c < 64; ++c) s += p[(size_t)c * EMBED];
  ws[WS_QKV + m * EMBED + j] = s;
}

// ---------------------------------------------------------------------------
// B: BLOCK-ROLE-SPECIALIZED shift + attention, one launch, 2048 blocks x 256.
//
//  blocks 0..1023   : attention role — R0's proven online-softmax body, but
//                     READ-ONLY (no cache-shift stores). Reads original cache
//                     rows t+1 (or the new token from ws). Writes only the
//                     16-float-per-head block partials.
//  blocks 1024..2047: copy role — pure grid-stride float4 memmove:
//                     out plane row r = cache plane row r+1 (r<16383),
//                     row 16383 = new token. Structured like the runtime's
//                     fill kernel, which sustains 6.7 TB/s on this machine.
//
// Rationale (R0-R5 evidence): traffic is at floor every round (66 MB fetch /
// 134 MB write); three pipeline variants of the FUSED load->store->reduce
// wave all pin at ~2.5-2.7 TB/s (~75us) because each wave round-trips
// load-latency + store-drain per 4KB. A pure store/copy stream doesn't wait.
// The two roles are data-independent (attention reads the ORIGINAL cache),
// so they overlap inside one kernel; attention reads ride L2/L3 (FETCH=66MB
// of a 134MB read already proves half the cache is L3-resident).
// All 2048 blocks co-resident: 8 blocks/CU, 102KB LDS/CU, VGPR<=64.
// ---------------------------------------------------------------------------
__global__ __launch_bounds__(256) void shift_attn(
    const float* __restrict__ cache,   // (2, 16384, 1024): v then k
    float* __restrict__ out,           // d_out
    float* __restrict__ ws) {
  __shared__ float sacc[3][EMBED];
  __shared__ float sm[4][NHEAD];
  __shared__ float sl[4][NHEAD];

  const int bid = blockIdx.x;

  if (bid >= 1024) {
    // ---------------- copy role ----------------
    const int cb    = bid - 1024;      // 0..1023
    const int plane = cb >> 9;         // 0: v, 1: k
    const int cbi   = cb & 511;        // 0..511 within plane
    const int tid   = threadIdx.x;
    const float* src = cache + (size_t)plane * CLEN * EMBED + EMBED;  // row 1
    float* dst = out + EMBED + (size_t)plane * CLEN * EMBED;          // row 0
    // 16383*1024 floats = 4,194,048 float4 per plane; 512 blk x 256 thr
    // = 131072 threads -> 32 float4/thread (last partial guarded).
    const int NT = 512 * 256;
#pragma unroll 4
    for (int i = 0; i < 32; ++i) {
      size_t e4 = (size_t)i * NT + cbi * 256 + tid;
      if (e4 < 4194048u) {
        size_t e = e4 * 4;
        *(float4*)(dst + e) = *(const float4*)(src + e);
      }
    }
    // final row (t = CLEN-1) = new token from ws
    if (cbi == 0 && tid < 256) {
      const float* tok = ws + WS_QKV + (plane == 0 ? 2 * EMBED : EMBED);
      *(float4*)(dst + (size_t)(CLEN - 1) * EMBED + tid * 4) =
          *(const float4*)(tok + tid * 4);
    }
    return;
  }

  // ---------------- attention role (read-only) ----------------
  const int wv   = threadIdx.x >> 6;   // wave in block 0..3
  const int lane = threadIdx.x & 63;
  const int grp  = lane >> 4;          // 16-lane group 0..3

  float qf[16];
#pragma unroll
  for (int c = 0; c < 4; ++c) {
    float4 t = *(const float4*)(ws + WS_QKV + c * 256 + lane * 4);
    qf[c * 4] = t.x; qf[c * 4 + 1] = t.y; qf[c * 4 + 2] = t.z; qf[c * 4 + 3] = t.w;
  }

  float m[4] = {-INFINITY, -INFINITY, -INFINITY, -INFINITY};
  float l[4] = {0.f, 0.f, 0.f, 0.f};
  float acc[16];
#pragma unroll
  for (int j = 0; j < 16; ++j) acc[j] = 0.f;

  const float* vin = cache;
  const float* kin = cache + (size_t)CLEN * EMBED;
  const int t0 = bid * 16 + wv * 4;

  for (int it = 0; it < 4; ++it) {
    int t = t0 + it;
    const float* vsrc = (t < CLEN - 1) ? (vin + (size_t)(t + 1) * EMBED)
                                       : (ws + WS_QKV + 2 * EMBED);
    const float* ksrc = (t < CLEN - 1) ? (kin + (size_t)(t + 1) * EMBED)
                                       : (ws + WS_QKV + EMBED);
    float vv[16], kk[16];
#pragma unroll
    for (int c = 0; c < 4; ++c) {
      float4 tv = *(const float4*)(vsrc + c * 256 + lane * 4);
      vv[c * 4] = tv.x; vv[c * 4 + 1] = tv.y; vv[c * 4 + 2] = tv.z; vv[c * 4 + 3] = tv.w;
    }
#pragma unroll
    for (int c = 0; c < 4; ++c) {
      float4 tk = *(const float4*)(ksrc + c * 256 + lane * 4);
      kk[c * 4] = tk.x; kk[c * 4 + 1] = tk.y; kk[c * 4 + 2] = tk.z; kk[c * 4 + 3] = tk.w;
    }

    bool nz = false;
#pragma unroll
    for (int j = 0; j < 16; ++j) nz = nz || (vv[j] != 0.f);

    // per-chunk partial dots, butterfly over the 16-lane group
    float d[4];
#pragma unroll
    for (int c = 0; c < 4; ++c) {
      d[c] = qf[c * 4] * kk[c * 4] + qf[c * 4 + 1] * kk[c * 4 + 1] +
             qf[c * 4 + 2] * kk[c * 4 + 2] + qf[c * 4 + 3] * kk[c * 4 + 3];
    }
#pragma unroll
    for (int msk = 1; msk <= 8; msk <<= 1) {
#pragma unroll
      for (int c = 0; c < 4; ++c) d[c] += __shfl_xor(d[c], msk, 64);
    }

    if (__any((int)nz)) {
#pragma unroll
      for (int c = 0; c < 4; ++c) {
        float s  = d[c] * 0.125f;              // 1/sqrt(64)
        float mn = fmaxf(m[c], s);
        float alpha = __expf(m[c] - mn);       // exp(-inf)=0 on first hit
        float p     = __expf(s - mn);
        l[c] = l[c] * alpha + p;
#pragma unroll
        for (int j = 0; j < 4; ++j)
          acc[c * 4 + j] = acc[c * 4 + j] * alpha + p * vv[c * 4 + j];
        m[c] = mn;
      }
    }
  }

  // intra-block combine: waves 1..3 park partials in LDS, wave 0 merges.
  if (wv > 0) {
#pragma unroll
    for (int c = 0; c < 4; ++c)
      *(float4*)(&sacc[wv - 1][c * 256 + lane * 4]) =
          make_float4(acc[c * 4], acc[c * 4 + 1], acc[c * 4 + 2], acc[c * 4 + 3]);
    if ((lane & 15) == 0) {
#pragma unroll
      for (int c = 0; c < 4; ++c) {
        sm[wv][c * 4 + grp] = m[c];
        sl[wv][c * 4 + grp] = l[c];
      }
    }
  }
  __syncthreads();
  if (wv == 0) {
    for (int w = 1; w < 4; ++w) {
#pragma unroll
      for (int c = 0; c < 4; ++c) {
        float m2 = sm[w][c * 4 + grp];
        float M  = fmaxf(m[c], m2);
        float a1 = (m[c] == -INFINITY) ? 0.f : __expf(m[c] - M);
        float a2 = (m2   == -INFINITY) ? 0.f : __expf(m2 - M);
        l[c] = a1 * l[c] + a2 * sl[w][c * 4 + grp];
        float4 av = *(const float4*)(&sacc[w - 1][c * 256 + lane * 4]);
        acc[c * 4]     = a1 * acc[c * 4]     + a2 * av.x;
        acc[c * 4 + 1] = a1 * acc[c * 4 + 1] + a2 * av.y;
        acc[c * 4 + 2] = a1 * acc[c * 4 + 2] + a2 * av.z;
        acc[c * 4 + 3] = a1 * acc[c * 4 + 3] + a2 * av.w;
        m[c] = M;
      }
    }
    if ((lane & 15) == 0) {
#pragma unroll
      for (int c = 0; c < 4; ++c) {
        ws[WS_PM + bid * NHEAD + c * 4 + grp] = m[c];
        ws[WS_PL + bid * NHEAD + c * 4 + grp] = l[c];
      }
    }
    float* pa = ws + WS_PACC + (size_t)bid * EMBED;
#pragma unroll
    for (int c = 0; c < 4; ++c)
      *(float4*)(pa + c * 256 + lane * 4) =
          make_float4(acc[c * 4], acc[c * 4 + 1], acc[c * 4 + 2], acc[c * 4 + 3]);
  }
}

// C1: 1024 block-partials -> 32 group-partials. 32 blocks x 1024.
__global__ __launch_bounds__(1024) void combine1(float* __restrict__ ws) {
  int g = blockIdx.x, t = threadIdx.x, h = t >> 6;
  int w0 = g * 32;
  float M = -INFINITY;
  for (int w = w0; w < w0 + 32; ++w)
    M = fmaxf(M, ws[WS_PM + w * NHEAD + h]);
  float L = 0.f, a = 0.f;
  for (int w = w0; w < w0 + 32; ++w) {
    float mw = ws[WS_PM + w * NHEAD + h];
    float sc = (mw == -INFINITY) ? 0.f : __expf(mw - M);
    L += sc * ws[WS_PL + w * NHEAD + h];
    a += sc * ws[WS_PACC + (size_t)w * EMBED + t];
  }
  if ((t & 63) == 0) {
    ws[WS_GM + g * NHEAD + h] = M;
    ws[WS_GL + g * NHEAD + h] = L;
  }
  ws[WS_GACC + (size_t)g * EMBED + t] = a;
}

// D (fused combine2 + out-proj partials): 64 blocks x 256.
__global__ __launch_bounds__(256) void out_proj(
    const float* __restrict__ Wo,
    float* __restrict__ ws) {
  __shared__ float svals[16];
  int c = blockIdx.x;
  int i0 = c * 16;
  int h0 = i0 >> 6;
  if (threadIdx.x < 16) {
    int i = i0 + threadIdx.x;
    float M = -INFINITY;
    for (int g = 0; g < 32; ++g)
      M = fmaxf(M, ws[WS_GM + g * NHEAD + h0]);
    float L = 0.f, a = 0.f;
    for (int g = 0; g < 32; ++g) {
      float mg = ws[WS_GM + g * NHEAD + h0];
      float sc = (mg == -INFINITY) ? 0.f : __expf(mg - M);
      L += sc * ws[WS_GL + g * NHEAD + h0];
      a += sc * ws[WS_GACC + (size_t)g * EMBED + i];
    }
    svals[threadIdx.x] = a / L;
  }
  __syncthreads();
  int j = threadIdx.x << 2;
  float4 acc = make_float4(0.f, 0.f, 0.f, 0.f);
  for (int i = 0; i < 16; ++i) {
    float xv = svals[i];
    float4 w = *(const float4*)(Wo + (size_t)(i0 + i) * EMBED + j);
    acc.x += xv * w.x; acc.y += xv * w.y;
    acc.z += xv * w.z; acc.w += xv * w.w;
  }
  *(float4*)(ws + WS_OPART + (size_t)c * EMBED + j) = acc;
}

// D2: reduce 64 partials + bo -> d_out[0:1024]. 1 block x 1024.
__global__ __launch_bounds__(1024) void out_reduce(
    const float* __restrict__ ws, const float* __restrict__ bo,
    float* __restrict__ out) {
  int t = threadIdx.x;
  float s = bo[t];
  const float* p = ws + WS_OPART + t;
  for (int c = 0; c < 64; ++c) s += p[(size_t)c * EMBED];
  out[t] = s;
}

extern "C" void kernel_launch(void* const* d_in, const int* in_sizes, int n_in,
                              void* d_out, int out_size, void* d_ws, size_t ws_size,
                              hipStream_t stream) {
  const float* x     = (const float*)d_in[0];
  const float* cache = (const float*)d_in[1];
  const float* Wv    = (const float*)d_in[2];
  const float* bv    = (const float*)d_in[3];
  const float* Wq    = (const float*)d_in[4];
  const float* bq    = (const float*)d_in[5];
  const float* Wk    = (const float*)d_in[6];
  const float* bk    = (const float*)d_in[7];
  const float* Wo    = (const float*)d_in[8];
  const float* bo    = (const float*)d_in[9];
  float* out = (float*)d_out;
  float* ws  = (float*)d_ws;

  qkv_proj  <<<192, 256, 0, stream>>>(x, Wq, Wk, Wv, ws);
  qkv_reduce<<<12, 256, 0, stream>>>(bq, bk, bv, ws);
  shift_attn<<<2048, 256, 0, stream>>>(cache, out, ws);
  combine1  <<<32, 1024, 0, stream>>>(ws);
  out_proj  <<<64, 256, 0, stream>>>(Wo, ws);
  out_reduce<<<1, 1024, 0, stream>>>(ws, bo, out);
}

// Round 7
// 286.991 us; speedup vs baseline: 1.0601x; 1.0601x over previous
//
#include <hip/hip_runtime.h>
#include <math.h>

#define EMBED 1024
#define NHEAD 16
#define HDIM  64
#define CLEN  16384

// ---- workspace layout (float offsets) ----
#define WS_QKV   0          // q[1024] | k_i[1024] | v_i[1024]
#define WS_QP    3072       // qkv split-K partials [3*64*1024]
#define WS_PM    199680     // block-partial m   [512*16]
#define WS_PL    216064     // block-partial l   [512*16]
#define WS_PACC  232448     // block-partial acc [512*1024]
#define WS_GM    1281024    // group m   [32*16]
#define WS_GL    1281536    // group l   [32*16]
#define WS_GACC  1282048    // group acc [32*1024]
#define WS_OPART 1314816    // out-proj partials [64*1024]
// total = 1380352 floats ~= 5.52 MB

// ---------------------------------------------------------------------------
// A: q/k/v projection split-K partials. 192 blocks = 3 matrices x 64 K-chunks
// ---------------------------------------------------------------------------
__global__ __launch_bounds__(256) void qkv_proj(
    const float* __restrict__ x,
    const float* __restrict__ Wq,
    const float* __restrict__ Wk,
    const float* __restrict__ Wv,
    float* __restrict__ ws) {
  int m = blockIdx.x >> 6;             // 0:q 1:k 2:v
  int c = blockIdx.x & 63;             // K-chunk
  const float* W = (m == 0) ? Wq : (m == 1) ? Wk : Wv;
  int j = threadIdx.x << 2;
  int i0 = c * 16;
  float4 acc = make_float4(0.f, 0.f, 0.f, 0.f);
  for (int i = i0; i < i0 + 16; ++i) {
    float xv = x[i];
    float4 w = *(const float4*)(W + (size_t)i * EMBED + j);
    acc.x += xv * w.x; acc.y += xv * w.y;
    acc.z += xv * w.z; acc.w += xv * w.w;
  }
  *(float4*)(ws + WS_QP + (size_t)(m * 64 + c) * EMBED + j) = acc;
}

// A2: reduce 64 partials + bias -> q/k/v. 12 blocks x 256.
__global__ __launch_bounds__(256) void qkv_reduce(
    const float* __restrict__ bq, const float* __restrict__ bk,
    const float* __restrict__ bv, float* __restrict__ ws) {
  int m = blockIdx.x >> 2;
  int j = ((blockIdx.x & 3) << 8) + threadIdx.x;
  const float* b = (m == 0) ? bq : (m == 1) ? bk : bv;
  float s = b[j];
  const float* p = ws + WS_QP + (size_t)m * 64 * EMBED + j;
  for (int c = 0; c < 64; ++c) s += p[(size_t)c * EMBED];
  ws[WS_QKV + m * EMBED + j] = s;
}

// ---------------------------------------------------------------------------
// B: fused cache-shift + online-softmax attention, BATCH-2 butterfly merge.
// 512 blocks x 256 threads; wave wv owns positions t0..t0+7, processed as
// 4 batches of 2 positions. Per batch: 16 loads in flight (2 full row-pairs,
// 2x the per-burst MLP of the R3 winner), both rows stored, 8 partial dots
// pushed through ONE 4-round __shfl_xor butterfly (serial DS-chain count per
// byte HALVED vs R3), then two independent softmax updates (ILP).
// __launch_bounds__(256, 2): VGPR cap 128 so both row-pairs stay live
// (R4 lesson: default bounds trims to 64 VGPR and re-serializes).
//
// History: fused variants 75-82us @2.5-2.9 TB/s (R0/R3/R4/R5); role-split
// R6 doubled FETCH (L3 thrash) -> fused read->write-same-row is load-bearing.
// Traffic at floor every round. This attacks the last untried axis: the
// per-iteration cross-lane serial chain.
// ---------------------------------------------------------------------------
__global__ __launch_bounds__(256, 2) void shift_attn(
    const float* __restrict__ cache,   // (2, 16384, 1024): v then k
    float* __restrict__ out,           // d_out
    float* __restrict__ ws) {
  __shared__ float sacc[3][EMBED];
  __shared__ float sm[4][NHEAD];
  __shared__ float sl[4][NHEAD];

  const int wv   = threadIdx.x >> 6;   // wave in block 0..3
  const int lane = threadIdx.x & 63;
  const int grp  = lane >> 4;          // 16-lane group 0..3

  float qf[16];
#pragma unroll
  for (int c = 0; c < 4; ++c) {
    float4 t = *(const float4*)(ws + WS_QKV + c * 256 + lane * 4);
    qf[c * 4] = t.x; qf[c * 4 + 1] = t.y; qf[c * 4 + 2] = t.z; qf[c * 4 + 3] = t.w;
  }

  float m[4] = {-INFINITY, -INFINITY, -INFINITY, -INFINITY};
  float l[4] = {0.f, 0.f, 0.f, 0.f};
  float acc[16];
#pragma unroll
  for (int j = 0; j < 16; ++j) acc[j] = 0.f;

  const float* vin = cache;
  const float* kin = cache + (size_t)CLEN * EMBED;
  float* vout = out + EMBED;
  float* kout = out + EMBED + (size_t)CLEN * EMBED;
  const int t0 = blockIdx.x * 32 + wv * 8;

  const float* vq = ws + WS_QKV + 2 * EMBED;   // v_i (new token)
  const float* kq = ws + WS_QKV + EMBED;       // k_i (new token)

#pragma unroll
  for (int b = 0; b < 4; ++b) {
    const int p0 = t0 + 2 * b;
    const int p1 = t0 + 2 * b + 1;
    const float* vs0 = (p0 < CLEN - 1) ? (vin + (size_t)(p0 + 1) * EMBED) : vq;
    const float* ks0 = (p0 < CLEN - 1) ? (kin + (size_t)(p0 + 1) * EMBED) : kq;
    const float* vs1 = (p1 < CLEN - 1) ? (vin + (size_t)(p1 + 1) * EMBED) : vq;
    const float* ks1 = (p1 < CLEN - 1) ? (kin + (size_t)(p1 + 1) * EMBED) : kq;

    // ---- load both row-pairs: 16 float4 loads issued back-to-back ----
    float va[16], ka[16], vb[16], kb[16];
#pragma unroll
    for (int c = 0; c < 4; ++c) {
      float4 t = *(const float4*)(vs0 + c * 256 + lane * 4);
      va[c * 4] = t.x; va[c * 4 + 1] = t.y; va[c * 4 + 2] = t.z; va[c * 4 + 3] = t.w;
    }
#pragma unroll
    for (int c = 0; c < 4; ++c) {
      float4 t = *(const float4*)(ks0 + c * 256 + lane * 4);
      ka[c * 4] = t.x; ka[c * 4 + 1] = t.y; ka[c * 4 + 2] = t.z; ka[c * 4 + 3] = t.w;
    }
#pragma unroll
    for (int c = 0; c < 4; ++c) {
      float4 t = *(const float4*)(vs1 + c * 256 + lane * 4);
      vb[c * 4] = t.x; vb[c * 4 + 1] = t.y; vb[c * 4 + 2] = t.z; vb[c * 4 + 3] = t.w;
    }
#pragma unroll
    for (int c = 0; c < 4; ++c) {
      float4 t = *(const float4*)(ks1 + c * 256 + lane * 4);
      kb[c * 4] = t.x; kb[c * 4 + 1] = t.y; kb[c * 4 + 2] = t.z; kb[c * 4 + 3] = t.w;
    }

    // ---- store both shifted rows ----
    float* vd0 = vout + (size_t)p0 * EMBED;
    float* kd0 = kout + (size_t)p0 * EMBED;
    float* vd1 = vout + (size_t)p1 * EMBED;
    float* kd1 = kout + (size_t)p1 * EMBED;
#pragma unroll
    for (int c = 0; c < 4; ++c)
      *(float4*)(vd0 + c * 256 + lane * 4) =
          make_float4(va[c * 4], va[c * 4 + 1], va[c * 4 + 2], va[c * 4 + 3]);
#pragma unroll
    for (int c = 0; c < 4; ++c)
      *(float4*)(kd0 + c * 256 + lane * 4) =
          make_float4(ka[c * 4], ka[c * 4 + 1], ka[c * 4 + 2], ka[c * 4 + 3]);
#pragma unroll
    for (int c = 0; c < 4; ++c)
      *(float4*)(vd1 + c * 256 + lane * 4) =
          make_float4(vb[c * 4], vb[c * 4 + 1], vb[c * 4 + 2], vb[c * 4 + 3]);
#pragma unroll
    for (int c = 0; c < 4; ++c)
      *(float4*)(kd1 + c * 256 + lane * 4) =
          make_float4(kb[c * 4], kb[c * 4 + 1], kb[c * 4 + 2], kb[c * 4 + 3]);

    bool nz0 = false, nz1 = false;
#pragma unroll
    for (int j = 0; j < 16; ++j) { nz0 = nz0 || (va[j] != 0.f); nz1 = nz1 || (vb[j] != 0.f); }

    // ---- 8 partial dots, ONE shared 4-round butterfly ----
    float d[8];
#pragma unroll
    for (int c = 0; c < 4; ++c) {
      d[c] = qf[c * 4] * ka[c * 4] + qf[c * 4 + 1] * ka[c * 4 + 1] +
             qf[c * 4 + 2] * ka[c * 4 + 2] + qf[c * 4 + 3] * ka[c * 4 + 3];
      d[c + 4] = qf[c * 4] * kb[c * 4] + qf[c * 4 + 1] * kb[c * 4 + 1] +
                 qf[c * 4 + 2] * kb[c * 4 + 2] + qf[c * 4 + 3] * kb[c * 4 + 3];
    }
#pragma unroll
    for (int msk = 1; msk <= 8; msk <<= 1) {
#pragma unroll
      for (int c = 0; c < 8; ++c) d[c] += __shfl_xor(d[c], msk, 64);
    }

    // ---- two independent online-softmax updates ----
    if (__any((int)nz0)) {
#pragma unroll
      for (int c = 0; c < 4; ++c) {
        float s  = d[c] * 0.125f;              // 1/sqrt(64)
        float mn = fmaxf(m[c], s);
        float alpha = __expf(m[c] - mn);       // exp(-inf)=0 on first hit
        float p     = __expf(s - mn);
        l[c] = l[c] * alpha + p;
#pragma unroll
        for (int j = 0; j < 4; ++j)
          acc[c * 4 + j] = acc[c * 4 + j] * alpha + p * va[c * 4 + j];
        m[c] = mn;
      }
    }
    if (__any((int)nz1)) {
#pragma unroll
      for (int c = 0; c < 4; ++c) {
        float s  = d[c + 4] * 0.125f;
        float mn = fmaxf(m[c], s);
        float alpha = __expf(m[c] - mn);
        float p     = __expf(s - mn);
        l[c] = l[c] * alpha + p;
#pragma unroll
        for (int j = 0; j < 4; ++j)
          acc[c * 4 + j] = acc[c * 4 + j] * alpha + p * vb[c * 4 + j];
        m[c] = mn;
      }
    }
  }

  // intra-block combine: waves 1..3 park partials in LDS, wave 0 merges.
  if (wv > 0) {
#pragma unroll
    for (int c = 0; c < 4; ++c)
      *(float4*)(&sacc[wv - 1][c * 256 + lane * 4]) =
          make_float4(acc[c * 4], acc[c * 4 + 1], acc[c * 4 + 2], acc[c * 4 + 3]);
    if ((lane & 15) == 0) {
#pragma unroll
      for (int c = 0; c < 4; ++c) {
        sm[wv][c * 4 + grp] = m[c];
        sl[wv][c * 4 + grp] = l[c];
      }
    }
  }
  __syncthreads();
  if (wv == 0) {
    for (int w = 1; w < 4; ++w) {
#pragma unroll
      for (int c = 0; c < 4; ++c) {
        float m2 = sm[w][c * 4 + grp];
        float M  = fmaxf(m[c], m2);
        float a1 = (m[c] == -INFINITY) ? 0.f : __expf(m[c] - M);
        float a2 = (m2   == -INFINITY) ? 0.f : __expf(m2 - M);
        l[c] = a1 * l[c] + a2 * sl[w][c * 4 + grp];
        float4 av = *(const float4*)(&sacc[w - 1][c * 256 + lane * 4]);
        acc[c * 4]     = a1 * acc[c * 4]     + a2 * av.x;
        acc[c * 4 + 1] = a1 * acc[c * 4 + 1] + a2 * av.y;
        acc[c * 4 + 2] = a1 * acc[c * 4 + 2] + a2 * av.z;
        acc[c * 4 + 3] = a1 * acc[c * 4 + 3] + a2 * av.w;
        m[c] = M;
      }
    }
    if ((lane & 15) == 0) {
#pragma unroll
      for (int c = 0; c < 4; ++c) {
        ws[WS_PM + blockIdx.x * NHEAD + c * 4 + grp] = m[c];
        ws[WS_PL + blockIdx.x * NHEAD + c * 4 + grp] = l[c];
      }
    }
    float* pa = ws + WS_PACC + (size_t)blockIdx.x * EMBED;
#pragma unroll
    for (int c = 0; c < 4; ++c)
      *(float4*)(pa + c * 256 + lane * 4) =
          make_float4(acc[c * 4], acc[c * 4 + 1], acc[c * 4 + 2], acc[c * 4 + 3]);
  }
}

// C1: 512 block-partials -> 32 group-partials. 32 blocks x 1024 (16 each).
__global__ __launch_bounds__(1024) void combine1(float* __restrict__ ws) {
  int g = blockIdx.x, t = threadIdx.x, h = t >> 6;
  int w0 = g * 16;
  float M = -INFINITY;
  for (int w = w0; w < w0 + 16; ++w)
    M = fmaxf(M, ws[WS_PM + w * NHEAD + h]);
  float L = 0.f, a = 0.f;
  for (int w = w0; w < w0 + 16; ++w) {
    float mw = ws[WS_PM + w * NHEAD + h];
    float sc = (mw == -INFINITY) ? 0.f : __expf(mw - M);
    L += sc * ws[WS_PL + w * NHEAD + h];
    a += sc * ws[WS_PACC + (size_t)w * EMBED + t];
  }
  if ((t & 63) == 0) {
    ws[WS_GM + g * NHEAD + h] = M;
    ws[WS_GL + g * NHEAD + h] = L;
  }
  ws[WS_GACC + (size_t)g * EMBED + t] = a;
}

// D (fused combine2 + out-proj partials): 64 blocks x 256.
__global__ __launch_bounds__(256) void out_proj(
    const float* __restrict__ Wo,
    float* __restrict__ ws) {
  __shared__ float svals[16];
  int c = blockIdx.x;
  int i0 = c * 16;
  int h0 = i0 >> 6;
  if (threadIdx.x < 16) {
    int i = i0 + threadIdx.x;
    float M = -INFINITY;
    for (int g = 0; g < 32; ++g)
      M = fmaxf(M, ws[WS_GM + g * NHEAD + h0]);
    float L = 0.f, a = 0.f;
    for (int g = 0; g < 32; ++g) {
      float mg = ws[WS_GM + g * NHEAD + h0];
      float sc = (mg == -INFINITY) ? 0.f : __expf(mg - M);
      L += sc * ws[WS_GL + g * NHEAD + h0];
      a += sc * ws[WS_GACC + (size_t)g * EMBED + i];
    }
    svals[threadIdx.x] = a / L;
  }
  __syncthreads();
  int j = threadIdx.x << 2;
  float4 acc = make_float4(0.f, 0.f, 0.f, 0.f);
  for (int i = 0; i < 16; ++i) {
    float xv = svals[i];
    float4 w = *(const float4*)(Wo + (size_t)(i0 + i) * EMBED + j);
    acc.x += xv * w.x; acc.y += xv * w.y;
    acc.z += xv * w.z; acc.w += xv * w.w;
  }
  *(float4*)(ws + WS_OPART + (size_t)c * EMBED + j) = acc;
}

// D2: reduce 64 partials + bo -> d_out[0:1024]. 1 block x 1024.
__global__ __launch_bounds__(1024) void out_reduce(
    const float* __restrict__ ws, const float* __restrict__ bo,
    float* __restrict__ out) {
  int t = threadIdx.x;
  float s = bo[t];
  const float* p = ws + WS_OPART + t;
  for (int c = 0; c < 64; ++c) s += p[(size_t)c * EMBED];
  out[t] = s;
}

extern "C" void kernel_launch(void* const* d_in, const int* in_sizes, int n_in,
                              void* d_out, int out_size, void* d_ws, size_t ws_size,
                              hipStream_t stream) {
  const float* x     = (const float*)d_in[0];
  const float* cache = (const float*)d_in[1];
  const float* Wv    = (const float*)d_in[2];
  const float* bv    = (const float*)d_in[3];
  const float* Wq    = (const float*)d_in[4];
  const float* bq    = (const float*)d_in[5];
  const float* Wk    = (const float*)d_in[6];
  const float* bk    = (const float*)d_in[7];
  const float* Wo    = (const float*)d_in[8];
  const float* bo    = (const float*)d_in[9];
  float* out = (float*)d_out;
  float* ws  = (float*)d_ws;

  qkv_proj  <<<192, 256, 0, stream>>>(x, Wq, Wk, Wv, ws);
  qkv_reduce<<<12, 256, 0, stream>>>(bq, bk, bv, ws);
  shift_attn<<<512, 256, 0, stream>>>(cache, out, ws);
  combine1  <<<32, 1024, 0, stream>>>(ws);
  out_proj  <<<64, 256, 0, stream>>>(Wo, ws);
  out_reduce<<<1, 1024, 0, stream>>>(ws, bo, out);
}